// Round 6
// baseline (691.164 us; speedup 1.0000x reference)
//
#include <hip/hip_runtime.h>
#include <cstdint>

#define K_IN   4096
#define N_OUT  4096
#define M_ROWS 16384
#define RANK   8
#define LSCALE 1.0f   // alpha/rank = 8/8
#define NT     64     // K_IN / 64  (BK=64 K-tiles)

typedef __attribute__((ext_vector_type(8))) short  short8;
typedef __attribute__((ext_vector_type(4))) float  floatx4;

__device__ __forceinline__ unsigned short f2bf(float f) {
  uint32_t u = __float_as_uint(f);
  u += 0x7FFFu + ((u >> 16) & 1u);
  return (unsigned short)(u >> 16);
}

__global__ __launch_bounds__(256) void fold_w_kernel(
    const float* __restrict__ W, const float* __restrict__ lA,
    const float* __restrict__ lB, unsigned short* __restrict__ Weff) {
  int idx = blockIdx.x * 256 + threadIdx.x;
  int o = idx >> 10;
  int k = (idx & 1023) << 2;
  float4 w = *reinterpret_cast<const float4*>(W + (size_t)o * K_IN + k);
#pragma unroll
  for (int r = 0; r < RANK; ++r) {
    float s = LSCALE * lB[o * RANK + r];
    float4 a = *reinterpret_cast<const float4*>(lA + r * K_IN + k);
    w.x += s * a.x; w.y += s * a.y; w.z += s * a.z; w.w += s * a.w;
  }
  ushort4 p;
  p.x = f2bf(w.x); p.y = f2bf(w.y); p.z = f2bf(w.z); p.w = f2bf(w.w);
  *reinterpret_cast<ushort4*>(Weff + (size_t)o * K_IN + k) = p;
}

__global__ __launch_bounds__(256) void cvt_x_kernel(
    const float* __restrict__ x, unsigned short* __restrict__ xb) {
  size_t i = ((size_t)blockIdx.x * 256 + threadIdx.x) * 8;
  float4 a = *reinterpret_cast<const float4*>(x + i);
  float4 c = *reinterpret_cast<const float4*>(x + i + 4);
  uint4 v;
  v.x = (uint32_t)f2bf(a.x) | ((uint32_t)f2bf(a.y) << 16);
  v.y = (uint32_t)f2bf(a.z) | ((uint32_t)f2bf(a.w) << 16);
  v.z = (uint32_t)f2bf(c.x) | ((uint32_t)f2bf(c.y) << 16);
  v.w = (uint32_t)f2bf(c.z) | ((uint32_t)f2bf(c.w) << 16);
  *reinterpret_cast<uint4*>(xb + i) = v;
}

__device__ __forceinline__ void gload_lds16(const void* g, void* l) {
  __builtin_amdgcn_global_load_lds(
      (const __attribute__((address_space(1))) void*)g,
      (__attribute__((address_space(3))) void*)l, 16, 0, 0);
}

// ---------------------------------------------------------------------------
// 256x256 tile, BK=64, 512 threads (8 waves: 2M x 4N), 4 phases/K-tile,
// double-buffered LDS (2 x 64KB), gload_lds staging, pre-swizzled source.
// ROUND-6 CHANGE: register-pipelined frags. Each phase issues the ds_reads
// for phase p+1, then MFMAs phase p's already-resident frags. No manual
// lgkmcnt — the compiler emits minimal counted lgkm waits for the
// one-phase-ahead dataflow. This overlaps the LDS pipe with the MFMA pipe,
// which round 5's [reads][bar][lgkm0][MFMA][bar] serialized (wall 5316 cyc
// per K-tile vs MFMA floor 2480 + LDS 2300 measured additive).
// Phase map (mh = M-half of wave tile, ks = K-half of tile):
//   pre-loop: read af(0,0), bf(0)
//   P0: read af(1,0)        | stage Ak0(t+1) | vm-cert | BAR | MFMA(0,0) | BAR
//   P1: read af(0,1), bf(1) | stage Bk0(t+1) |         | BAR | MFMA(1,0) | BAR
//   P2: read af(1,1)        | stage Ak1(t+1) | vm-cert | BAR | MFMA(0,1) | BAR
//   P3: read af(0,0),bf(0) of t+1 | stage Bk1(t+1)     | BAR | MFMA(1,1) | BAR
// vmcnt ledger (2 loads per STAGE per thread, in-order retirement):
//   P0-end: outstanding {Ak1,Bk1}(t),{Ak0}(t+1)=6 -> vmcnt(2) certifies
//           {Ak1,Bk1}(t) before P1 reads them (2 barriers later). tail: vmcnt(0).
//   P2-end: outstanding {Ak0,Bk0,Ak1}(t+1)=6 -> vmcnt(2) certifies
//           {Ak0,Bk0}(t+1) before P3 reads them. tail: skip.
// WAR audit: a region's reads complete (compiler lgkm wait before the next
// phase's MFMA) >=2 barriers before any re-staging DMA into it is issued.
// Frag regs: named ping-pong sets (compile-time indexed, rule #20).
// ---------------------------------------------------------------------------
__global__ __launch_bounds__(512, 2) void gemm_kernel(
    const unsigned short* __restrict__ Xb, const unsigned short* __restrict__ Wb,
    const float* __restrict__ bias, float* __restrict__ out) {
  __shared__ alignas(16) char lds[2 * 65536];   // 128 KiB

  const int tid  = threadIdx.x;
  const int wave = tid >> 6, lane = tid & 63;
  const int wr = wave >> 2, wc = wave & 3;      // 2 (M) x 4 (N) wave grid
  const int l15 = lane & 15, sq = lane >> 4;
  const int xorv = (l15 & 7) << 4;

  // XCD swizzle: 1024 blocks (%8==0), contiguous 128-tile chunk per XCD
  int bx  = blockIdx.x;
  int sbx = (bx & 7) * 128 + (bx >> 3);
  const int mt = sbx >> 4;   // 0..63
  const int nt = sbx & 15;   // 0..15

  // staging source pre-swizzle: linear LDS byte L -> logical (r,s):
  //   r = (L>>7)*2 | ((L>>6 ^ L>>8)&1),  s = ((L>>4)&3) ^ (r&3)
  const unsigned short *gA0, *gA1, *gB0, *gB1;
  {
    int L0 = tid * 16;
    int r0 = ((L0 >> 7) << 1) | (((L0 >> 6) ^ (L0 >> 8)) & 1);
    int s0 = ((L0 >> 4) & 3) ^ (r0 & 3);
    gA0 = Xb + (size_t)(mt * 256 + r0) * K_IN + s0 * 8;
    gB0 = Wb + (size_t)(nt * 256 + r0) * K_IN + s0 * 8;
    int L1 = 8192 + tid * 16;
    int r1 = ((L1 >> 7) << 1) | (((L1 >> 6) ^ (L1 >> 8)) & 1);
    int s1 = ((L1 >> 4) & 3) ^ (r1 & 3);
    gA1 = Xb + (size_t)(mt * 256 + r1) * K_IN + s1 * 8;
    gB1 = Wb + (size_t)(nt * 256 + r1) * K_IN + s1 * 8;
  }

#define STAGE_A(TT, KS) do {                                         \
    char* d_ = lds + ((TT) & 1) * 65536 + (KS) * 16384 + tid * 16;   \
    gload_lds16(gA0 + (TT) * 64 + (KS) * 32, d_);                    \
    gload_lds16(gA1 + (TT) * 64 + (KS) * 32, d_ + 8192);             \
  } while (0)
#define STAGE_B(TT, KS) do {                                         \
    char* d_ = lds + ((TT) & 1) * 65536 + 32768 + (KS) * 16384 + tid * 16; \
    gload_lds16(gB0 + (TT) * 64 + (KS) * 32, d_);                    \
    gload_lds16(gB1 + (TT) * 64 + (KS) * 32, d_ + 8192);             \
  } while (0)
#define BAR() do { asm volatile("" ::: "memory");                    \
    __builtin_amdgcn_s_barrier();                                    \
    asm volatile("" ::: "memory"); } while (0)
#define LOAD_AF(DST, BASE, MH, KS) do {                              \
    const char* Ah_ = lds + (BASE) + (KS) * 16384;                   \
    _Pragma("unroll")                                                \
    for (int i = 0; i < 4; ++i) {                                    \
      int rA_ = wr * 128 + ((MH) * 4 + i) * 16 + l15;                \
      int LA_ = ((rA_ << 6) | (sq << 4)) ^ xorv;                     \
      DST[i] = *reinterpret_cast<const short8*>(Ah_ + LA_);          \
    } } while (0)
#define LOAD_BF(DST, BASE, KS) do {                                  \
    const char* Bh_ = lds + (BASE) + 32768 + (KS) * 16384;           \
    _Pragma("unroll")                                                \
    for (int j = 0; j < 4; ++j) {                                    \
      int rB_ = wc * 64 + j * 16 + l15;                              \
      int LB_ = ((rB_ << 6) | (sq << 4)) ^ xorv;                     \
      DST[j] = *reinterpret_cast<const short8*>(Bh_ + LB_);          \
    } } while (0)
#define DO_MFMA(MH, AF, BF) do {                                     \
    __builtin_amdgcn_s_setprio(1);                                   \
    _Pragma("unroll")                                                \
    for (int i = 0; i < 4; ++i)                                      \
      _Pragma("unroll")                                              \
      for (int j = 0; j < 4; ++j)                                    \
        acc[(MH) * 4 + i][j] = __builtin_amdgcn_mfma_f32_16x16x32_bf16( \
            AF[i], BF[j], acc[(MH) * 4 + i][j], 0, 0, 0);            \
    __builtin_amdgcn_s_setprio(0); } while (0)

  floatx4 acc[8][4];
#pragma unroll
  for (int i = 0; i < 8; ++i)
#pragma unroll
    for (int j = 0; j < 4; ++j)
      acc[i][j] = (floatx4){0.f, 0.f, 0.f, 0.f};

  // prologue: stage all 4 halves of t=0; certify {Ak0,Bk0}(0); pre-read P0 frags
  STAGE_A(0, 0); STAGE_B(0, 0); STAGE_A(0, 1); STAGE_B(0, 1);
  asm volatile("s_waitcnt vmcnt(4)" ::: "memory");
  BAR();

  short8 afA[4], afB[4], bfA[4], bfB[4];
  LOAD_AF(afA, 0, 0, 0);
  LOAD_BF(bfA, 0, 0);

  for (int t = 0; t < NT; ++t) {
    const int tb = (t & 1) * 65536;
    const int nb = tb ^ 65536;
    const bool more = (t + 1 < NT);

    // ---- P0: read af(1,0); stage Ak0(t+1); cert {Ak1,Bk1}(t); MFMA(0,0)
    LOAD_AF(afB, tb, 1, 0);
    if (more) {
      STAGE_A(t + 1, 0);
      asm volatile("s_waitcnt vmcnt(2)" ::: "memory");
    } else {
      asm volatile("s_waitcnt vmcnt(0)" ::: "memory");
    }
    BAR();
    DO_MFMA(0, afA, bfA);
    BAR();

    // ---- P1: read af(0,1), bf(1); stage Bk0(t+1); MFMA(1,0)
    LOAD_AF(afA, tb, 0, 1);
    LOAD_BF(bfB, tb, 1);
    if (more) STAGE_B(t + 1, 0);
    BAR();
    DO_MFMA(1, afB, bfA);
    BAR();

    // ---- P2: read af(1,1); stage Ak1(t+1); cert {Ak0,Bk0}(t+1); MFMA(0,1)
    LOAD_AF(afB, tb, 1, 1);
    if (more) {
      STAGE_A(t + 1, 1);
      asm volatile("s_waitcnt vmcnt(2)" ::: "memory");
    }
    BAR();
    DO_MFMA(0, afA, bfB);
    BAR();

    // ---- P3: read af(0,0), bf(0) of t+1; stage Bk1(t+1); MFMA(1,1)
    if (more) {
      LOAD_AF(afA, nb, 0, 0);
      LOAD_BF(bfA, nb, 0);
      STAGE_B(t + 1, 1);
    }
    BAR();
    DO_MFMA(1, afB, bfB);
    BAR();
  }
#undef STAGE_A
#undef STAGE_B
#undef LOAD_AF
#undef LOAD_BF
#undef DO_MFMA

  // epilogue: C/D layout col=lane&15, row=(lane>>4)*4+reg (m89/m91 verified)
  const int row0 = mt * 256 + wr * 128 + sq * 4;
  const int col0 = nt * 256 + wc * 64 + l15;
#pragma unroll
  for (int j = 0; j < 4; ++j) {
    int col = col0 + j * 16;
    float bv = bias[col];
#pragma unroll
    for (int i = 0; i < 8; ++i) {
      int rowb = row0 + i * 16;
#pragma unroll
      for (int rr = 0; rr < 4; ++rr)
        out[(size_t)(rowb + rr) * N_OUT + col] = acc[i][j][rr] + bv;
    }
  }
}

// self-contained correct fallback (only if ws too small): tiled fp32
__global__ __launch_bounds__(256) void fallback_kernel(
    const float* __restrict__ x, const float* __restrict__ W,
    const float* __restrict__ bias, const float* __restrict__ lA,
    const float* __restrict__ lB, float* __restrict__ out) {
  __shared__ float Xs[64][17];
  __shared__ float Ws[64][17];
  int tid = threadIdx.x;
  int tx = tid & 15, ty = tid >> 4;
  int bm = blockIdx.y * 64, bn = blockIdx.x * 64;
  float acc[4][4] = {};
  for (int k0 = 0; k0 < K_IN; k0 += 16) {
#pragma unroll
    for (int q = 0; q < 4; ++q) {
      int flat = q * 256 + tid;
      int r = flat >> 4, c = flat & 15;
      Xs[r][c] = x[(size_t)(bm + r) * K_IN + k0 + c];
      float w = W[(size_t)(bn + r) * K_IN + k0 + c];
#pragma unroll
      for (int rr = 0; rr < RANK; ++rr)
        w += LSCALE * lB[(bn + r) * RANK + rr] * lA[rr * K_IN + k0 + c];
      Ws[r][c] = w;
    }
    __syncthreads();
#pragma unroll
    for (int kk = 0; kk < 16; ++kk) {
      float av[4], bv[4];
#pragma unroll
      for (int i = 0; i < 4; ++i) av[i] = Xs[ty * 4 + i][kk];
#pragma unroll
      for (int j = 0; j < 4; ++j) bv[j] = Ws[tx * 4 + j][kk];
#pragma unroll
      for (int i = 0; i < 4; ++i)
#pragma unroll
        for (int j = 0; j < 4; ++j) acc[i][j] += av[i] * bv[j];
    }
    __syncthreads();
  }
#pragma unroll
  for (int i = 0; i < 4; ++i)
#pragma unroll
    for (int j = 0; j < 4; ++j)
      out[(size_t)(bm + ty * 4 + i) * N_OUT + bn + tx * 4 + j] =
          acc[i][j] + bias[bn + tx * 4 + j];
}

extern "C" void kernel_launch(void* const* d_in, const int* in_sizes, int n_in,
                              void* d_out, int out_size, void* d_ws, size_t ws_size,
                              hipStream_t stream) {
  const float* x  = (const float*)d_in[0];
  const float* W  = (const float*)d_in[1];
  const float* b  = (const float*)d_in[2];
  const float* lA = (const float*)d_in[3];
  const float* lB = (const float*)d_in[4];
  float* out = (float*)d_out;

  const size_t weff_bytes = (size_t)N_OUT * K_IN * 2;    // 32 MB
  const size_t xb_bytes   = (size_t)M_ROWS * K_IN * 2;   // 128 MB

  if (ws_size >= weff_bytes + xb_bytes) {
    unsigned short* Weff = (unsigned short*)d_ws;
    unsigned short* Xb   = (unsigned short*)((char*)d_ws + weff_bytes);
    fold_w_kernel<<<(int)(((size_t)N_OUT * K_IN / 4) / 256), 256, 0, stream>>>(W, lA, lB, Weff);
    cvt_x_kernel<<<(int)(((size_t)M_ROWS * K_IN / 8) / 256), 256, 0, stream>>>(x, Xb);
    gemm_kernel<<<(M_ROWS / 256) * (N_OUT / 256), 512, 0, stream>>>(Xb, Weff, b, out);
  } else {
    dim3 grid(N_OUT / 64, M_ROWS / 64);
    fallback_kernel<<<grid, 256, 0, stream>>>(x, W, b, lA, lB, out);
  }
}